// Round 1
// baseline (669.248 us; speedup 1.0000x reference)
//
#include <hip/hip_runtime.h>

// CTC loss (warp-ctc 'mean' reduction) on MI355X.
// Phase 1: per-(t,b) log-softmax denominator + gather of extended-label probs
//          p_ext[b][t][s] = exp(act[t,b,ext[s]] - lse(t,b)), padded to stride 256 with 0.
// Phase 2: linear-space alpha recursion, one wave per utterance, 4 states/lane,
//          periodic 2^-e renormalization (integer exponent accumulator).
// Phase 3: tiny reduction to the scalar output.

#define BLK 256

__global__ __launch_bounds__(BLK) void k_lse_gather(
    const float* __restrict__ act, const int* __restrict__ targets,
    float* __restrict__ p_ext, int T, int B, int C, int L, int S)
{
  int row = blockIdx.x;            // row = t*B + b  (act is [T,B,C] row-major)
  int b = row % B;
  int t = row / B;
  int tid = threadIdx.x;
  const float* rp = act + (size_t)row * (size_t)C;
  const float4* rp4 = (const float4*)rp;
  int C4 = C >> 2;                 // C assumed % 4 == 0 (C = 2000)

  // pass A: per-thread max over its <=4 float4 chunks, kept in registers
  float4 v[4];
  int nv = 0;
  float m = -3.0e38f;
  for (int i = tid; i < C4; i += BLK) {
    float4 x = rp4[i];
    if (nv < 4) v[nv] = x;
    nv++;
    m = fmaxf(m, fmaxf(fmaxf(x.x, x.y), fmaxf(x.z, x.w)));
  }
  #pragma unroll
  for (int o = 32; o > 0; o >>= 1) m = fmaxf(m, __shfl_xor(m, o));
  __shared__ float sm[BLK / 64];
  __shared__ float ss[BLK / 64];
  int w = tid >> 6, ln = tid & 63;
  if (ln == 0) sm[w] = m;
  __syncthreads();
  float M = fmaxf(fmaxf(sm[0], sm[1]), fmaxf(sm[2], sm[3]));

  // pass B: sum of exp(x - M) from registers
  float ssum = 0.f;
  int cnt = nv < 4 ? nv : 4;
  for (int k = 0; k < cnt; k++) {
    float4 x = v[k];
    ssum += expf(x.x - M) + expf(x.y - M) + expf(x.z - M) + expf(x.w - M);
  }
  #pragma unroll
  for (int o = 32; o > 0; o >>= 1) ssum += __shfl_xor(ssum, o);
  if (ln == 0) ss[w] = ssum;
  __syncthreads();
  float tot = ss[0] + ss[1] + ss[2] + ss[3];
  float lse = M + logf(tot);

  // gather extended-label probabilities; pad slots [S,256) with 0 so that
  // invalid DP states stay exactly 0 in phase 2.
  float* op = p_ext + ((size_t)b * T + t) * 256;
  int s = tid;                      // BLK == 256 covers all slots exactly once
  float p = 0.f;
  if (s < S) {
    int c = (s & 1) ? targets[b * L + (s >> 1)] : 0;   // blank == 0
    p = expf(rp[c] - lse);
  }
  op[s] = p;
}

__global__ __launch_bounds__(64) void k_alpha(
    const float* __restrict__ p_ext, const int* __restrict__ targets,
    const int* __restrict__ ilen, const int* __restrict__ tlen,
    float* __restrict__ costs, int T, int B, int L)
{
  int b = blockIdx.x;
  int l = threadIdx.x;              // lane 0..63 owns states 4l..4l+3
  int Tb = ilen[b];
  int Lb = tlen[b];
  int S = 2 * Lb + 1;

  const float4* pb = (const float4*)(p_ext + (size_t)b * (size_t)T * 256);

  // skip-transition flags: only odd states (labels) can skip; for slot1 the
  // s-2 value is prev-lane slot3 (u3), for slot3 it is this lane's slot1.
  bool k1 = false, k3 = false;
  {
    int i1 = 2 * l;                 // s = 4l+1
    if (4 * l + 1 < S)
      k1 = (i1 == 0) ? true : (targets[b * L + i1] != targets[b * L + i1 - 1]);
    int i3 = 2 * l + 1;             // s = 4l+3
    if (4 * l + 3 < S)
      k3 = (targets[b * L + i3] != targets[b * L + i3 - 1]);
  }

  // t = 0 init: alpha[0] = p(blank), alpha[1] = p(label0), rest 0.
  float a0 = 0.f, a1 = 0.f, a2 = 0.f, a3 = 0.f;
  {
    float4 p0 = pb[l];
    if (l == 0) { a0 = p0.x; a1 = p0.y; }
  }
  int E = 0;                        // true alpha = stored * 2^E (wave-uniform)

  const int PF = 8;                 // prefetch depth (float4 each)
  float4 pf[PF];
  #pragma unroll
  for (int j = 0; j < PF; j++) {
    int tt = 1 + j;
    pf[j] = (tt < Tb) ? pb[(size_t)tt * 64 + l] : make_float4(0.f, 0.f, 0.f, 0.f);
  }

  int t = 1;
  while (t < Tb) {
    #pragma unroll
    for (int j = 0; j < PF; j++) {
      int tt = t + j;
      if (tt < Tb) {                // wave-uniform condition
        float4 p = pf[j];
        int tn = tt + PF;
        pf[j] = (tn < Tb) ? pb[(size_t)tn * 64 + l] : make_float4(0.f, 0.f, 0.f, 0.f);

        float u3 = __shfl_up(a3, 1);      // alpha[4l-1] from prev lane
        if (l == 0) u3 = 0.f;
        float n0 = (a0 + u3) * p.x;                       // blank: no skip
        float n1 = (a1 + a0 + (k1 ? u3 : 0.f)) * p.y;     // label
        float n2 = (a2 + a1) * p.z;                       // blank: no skip
        float n3 = (a3 + a2 + (k3 ? a1 : 0.f)) * p.w;     // label
        a0 = n0; a1 = n1; a2 = n2; a3 = n3;

        if ((j & 3) == 3) {         // renormalize every 4 steps
          float mx = fmaxf(fmaxf(a0, a1), fmaxf(a2, a3));
          #pragma unroll
          for (int o = 32; o > 0; o >>= 1) mx = fmaxf(mx, __shfl_xor(mx, o));
          int e = ilogbf(fmaxf(mx, 1e-37f));
          a0 = ldexpf(a0, -e); a1 = ldexpf(a1, -e);
          a2 = ldexpf(a2, -e); a3 = ldexpf(a3, -e);
          E += e;
        }
      }
    }
    t += PF;
  }

  __shared__ float sA[260];
  sA[4 * l + 0] = a0; sA[4 * l + 1] = a1;
  sA[4 * l + 2] = a2; sA[4 * l + 3] = a3;
  __syncthreads();
  if (l == 0) {
    float ab = sA[2 * Lb];          // final blank state
    float al_ = sA[2 * Lb - 1];     // final label state
    float cost = -(logf(ab + al_) + (float)E * 0.69314718055994531f);
    costs[b] = cost;
  }
}

__global__ __launch_bounds__(64) void k_final(
    const float* __restrict__ costs, const int* __restrict__ tlen,
    float* __restrict__ out, int B)
{
  int i = threadIdx.x;
  float c = (i < B) ? costs[i] : 0.f;
  float tl = (i < B) ? (float)tlen[i] : 0.f;
  #pragma unroll
  for (int o = 32; o > 0; o >>= 1) {
    c += __shfl_xor(c, o);
    tl += __shfl_xor(tl, o);
  }
  if (i == 0) out[0] = c / (float)B / tl;
}

extern "C" void kernel_launch(void* const* d_in, const int* in_sizes, int n_in,
                              void* d_out, int out_size, void* d_ws, size_t ws_size,
                              hipStream_t stream) {
  const float* act     = (const float*)d_in[0];   // [T,B,C] fp32
  const int*   targets = (const int*)d_in[1];     // [B*L]
  const int*   ilen    = (const int*)d_in[2];     // [B]
  const int*   tlen    = (const int*)d_in[3];     // [B]
  float* out = (float*)d_out;

  int B = in_sizes[2];
  int L = in_sizes[1] / B;
  // T and C are not separable from in_sizes[0] = T*B*C; fixed by the problem.
  const int T = 1000, C = 2000;
  int S = 2 * L + 1;                // 201 <= 256 (one wave, 4 states/lane)

  float* p_ext = (float*)d_ws;                          // B*T*256 floats (~32.8 MB)
  float* costs = p_ext + (size_t)B * (size_t)T * 256;   // B floats

  k_lse_gather<<<T * B, BLK, 0, stream>>>(act, targets, p_ext, T, B, C, L, S);
  k_alpha<<<B, 64, 0, stream>>>(p_ext, targets, ilen, tlen, costs, T, B, L);
  k_final<<<1, 64, 0, stream>>>(costs, tlen, out, B);
}

// Round 3
// 539.025 us; speedup vs baseline: 1.2416x; 1.2416x over previous
//
#include <hip/hip_runtime.h>
#include <math.h>

// CTC loss (warp-ctc 'mean' reduction) on MI355X.
// Phase 1: per-(t,b) log-softmax denom + gather extended-label probs
//          p_ext[b][t][s] = exp(act[t,b,ext[s]] - lse), stride 256, pad 0.
// Phase 2: linear-space alpha recursion, 1 wave/utterance, 4 states/lane,
//          2 DP steps per lane-exchange (halo recompute). Renormalize every
//          4 steps to max ~ 2^64 (biased target keeps transient dips far from
//          the fp32 flush-to-zero floor; integer exponent accumulator E).
// Phase 3: double-precision reduction to the scalar.

#define BLK 256

__global__ __launch_bounds__(BLK) void k_lse_gather(
    const float* __restrict__ act, const int* __restrict__ targets,
    float* __restrict__ p_ext, int T, int B, int C, int L, int S)
{
  int row = blockIdx.x;            // row = t*B + b  (act is [T,B,C])
  int b = row % B;
  int t = row / B;
  int tid = threadIdx.x;
  const float* rp = act + (size_t)row * (size_t)C;
  const float4* rp4 = (const float4*)rp;
  int C4 = C >> 2;                 // 500 for C=2000

  // pass A: max. Two statically-addressed register chunks (C4 <= 2*BLK here);
  // generic overflow loop kept for safety (never taken at C=2000).
  float4 x0 = (tid < C4) ? rp4[tid] : make_float4(-3e38f, -3e38f, -3e38f, -3e38f);
  bool h2 = (tid + BLK) < C4;
  float4 x1 = h2 ? rp4[tid + BLK] : make_float4(0.f, 0.f, 0.f, 0.f);
  float m = fmaxf(fmaxf(x0.x, x0.y), fmaxf(x0.z, x0.w));
  if (h2) m = fmaxf(m, fmaxf(fmaxf(x1.x, x1.y), fmaxf(x1.z, x1.w)));
  for (int i = tid + 2 * BLK; i < C4; i += BLK) {
    float4 x = rp4[i];
    m = fmaxf(m, fmaxf(fmaxf(x.x, x.y), fmaxf(x.z, x.w)));
  }
  #pragma unroll
  for (int o = 32; o > 0; o >>= 1) m = fmaxf(m, __shfl_xor(m, o));
  __shared__ float sm[BLK / 64];
  __shared__ float ss[BLK / 64];
  int w = tid >> 6, ln = tid & 63;
  if (ln == 0) sm[w] = m;
  __syncthreads();
  float M = fmaxf(fmaxf(sm[0], sm[1]), fmaxf(sm[2], sm[3]));

  // pass B: sum exp(x - M) from registers
  float ssum = 0.f;
  if (tid < C4)
    ssum += expf(x0.x - M) + expf(x0.y - M) + expf(x0.z - M) + expf(x0.w - M);
  if (h2)
    ssum += expf(x1.x - M) + expf(x1.y - M) + expf(x1.z - M) + expf(x1.w - M);
  for (int i = tid + 2 * BLK; i < C4; i += BLK) {
    float4 x = rp4[i];
    ssum += expf(x.x - M) + expf(x.y - M) + expf(x.z - M) + expf(x.w - M);
  }
  #pragma unroll
  for (int o = 32; o > 0; o >>= 1) ssum += __shfl_xor(ssum, o);
  if (ln == 0) ss[w] = ssum;
  __syncthreads();
  float lse = M + logf(ss[0] + ss[1] + ss[2] + ss[3]);

  // gather; pad slots [S,256) with 0 so invalid DP states stay exactly 0.
  float* op = p_ext + ((size_t)b * T + t) * 256;
  float p = 0.f;
  if (tid < S) {
    int c = (tid & 1) ? targets[b * L + (tid >> 1)] : 0;   // blank == 0
    p = expf(rp[c] - lse);
  }
  op[tid] = p;
}

// 64-lane max reduction, pure DPP (no DS latency); returns uniform value.
// All inputs are >= 0 (alphas), so bound_ctrl-zeros are harmless under max.
__device__ __forceinline__ float wave_max64(float x) {
  int t;
  t = __builtin_amdgcn_update_dpp(0, __float_as_int(x), 0x111, 0xF, 0xF, true);  // row_shr:1
  x = fmaxf(x, __int_as_float(t));
  t = __builtin_amdgcn_update_dpp(0, __float_as_int(x), 0x112, 0xF, 0xF, true);  // row_shr:2
  x = fmaxf(x, __int_as_float(t));
  t = __builtin_amdgcn_update_dpp(0, __float_as_int(x), 0x114, 0xF, 0xF, true);  // row_shr:4
  x = fmaxf(x, __int_as_float(t));
  t = __builtin_amdgcn_update_dpp(0, __float_as_int(x), 0x118, 0xF, 0xF, true);  // row_shr:8
  x = fmaxf(x, __int_as_float(t));
  t = __builtin_amdgcn_update_dpp(0, __float_as_int(x), 0x142, 0xA, 0xF, false); // row_bcast:15
  x = fmaxf(x, __int_as_float(t));
  t = __builtin_amdgcn_update_dpp(0, __float_as_int(x), 0x143, 0xC, 0xF, false); // row_bcast:31
  x = fmaxf(x, __int_as_float(t));
  return __int_as_float(__builtin_amdgcn_readlane(__float_as_int(x), 63));
}

__global__ __launch_bounds__(64) void k_alpha(
    const float* __restrict__ p_ext, const int* __restrict__ targets,
    const int* __restrict__ ilen, const int* __restrict__ tlen,
    double* __restrict__ costs, int T, int B, int L)
{
  int b = blockIdx.x;
  int l = threadIdx.x;              // lane owns states 4l..4l+3
  int Tb = ilen[b];
  int Lb = tlen[b];
  int S = 2 * Lb + 1;

  const float4* pb4 = (const float4*)(p_ext + (size_t)b * (size_t)T * 256);

  // skip flags (0/1 floats) for the odd states this lane updates:
  // kf3 -> state 4l-1 (halo recompute), kf5 -> 4l+1, kf7 -> 4l+3.
  const int* tg = targets + b * L;
  float kf3 = 0.f, kf5 = 0.f, kf7 = 0.f;
  {
    int s;
    s = 4 * l - 1; if (s >= 3 && s < S) { int mm = (s - 1) >> 1; kf3 = (tg[mm] != tg[mm - 1]) ? 1.f : 0.f; }
    s = 4 * l + 1; if (s >= 3 && s < S) { int mm = (s - 1) >> 1; kf5 = (tg[mm] != tg[mm - 1]) ? 1.f : 0.f; }
    s = 4 * l + 3; if (s >= 3 && s < S) { int mm = (s - 1) >> 1; kf7 = (tg[mm] != tg[mm - 1]) ? 1.f : 0.f; }
  }

  // t = 0 init, pre-biased to 2^64 (true alpha = stored * 2^E).
  const float BIAS = 18446744073709551616.0f;   // 2^64
  float a0 = 0.f, a1 = 0.f, a2 = 0.f, a3 = 0.f;
  {
    float4 p0 = pb4[l];
    if (l == 0) { a0 = p0.x * BIAS; a1 = p0.y * BIAS; }
  }
  int E = -64;

  int i0 = (l == 0) ? 0 : (l - 1); // halo float4 index (lane0 halo is 0 anyway)

  const int PF = 8;                 // prefetch depth in exchanges (16 steps)
  int NE = (Tb - 1) >> 1;           // full 2-step exchanges
  float4 fa[PF], fb[PF], fc[PF];    // halo@t, own@t, own@t+1
  #pragma unroll
  for (int j = 0; j < PF; j++) {
    int t0 = 1 + 2 * j;
    if (j < NE) {
      fa[j] = pb4[(size_t)t0 * 64 + i0];
      fb[j] = pb4[(size_t)t0 * 64 + l];
      fc[j] = pb4[(size_t)(t0 + 1) * 64 + l];
    } else {
      fa[j] = fb[j] = fc[j] = make_float4(0.f, 0.f, 0.f, 0.f);
    }
  }

  int e = 0;
  while (e < NE) {
    #pragma unroll
    for (int j = 0; j < PF; j++) {
      int eg = e + j;
      if (eg < NE) {                // wave-uniform
        float4 Pa = fa[j], Pb = fb[j], Pc = fc[j];
        int en = eg + PF;
        if (en < NE) {
          int tn = 1 + 2 * en;
          fa[j] = pb4[(size_t)tn * 64 + i0];
          fb[j] = pb4[(size_t)tn * 64 + l];
          fc[j] = pb4[(size_t)(tn + 1) * 64 + l];
        }

        // halo: w0..w3 = prev lane's a0..a3 (4 parallel shuffles)
        float w0 = __shfl_up(a0, 1), w1 = __shfl_up(a1, 1);
        float w2 = __shfl_up(a2, 1), w3 = __shfl_up(a3, 1);
        if (l == 0) { w0 = 0.f; w1 = 0.f; w2 = 0.f; w3 = 0.f; }
        float w4 = a0, w5 = a1, w6 = a2, w7 = a3;

        // step 1 (time t): in-place descending update of window i=7..2
        w7 = (w7 + w6 + kf7 * w5) * Pb.w;
        w6 = (w6 + w5) * Pb.z;
        w5 = (w5 + w4 + kf5 * w3) * Pb.y;
        w4 = (w4 + w3) * Pb.x;
        w3 = (w3 + w2 + kf3 * w1) * Pa.w;
        w2 = (w2 + w1) * Pa.z;
        // step 2 (time t+1): own states only
        w7 = (w7 + w6 + kf7 * w5) * Pc.w;
        w6 = (w6 + w5) * Pc.z;
        w5 = (w5 + w4 + kf5 * w3) * Pc.y;
        w4 = (w4 + w3) * Pc.x;
        a0 = w4; a1 = w5; a2 = w6; a3 = w7;

        if ((j & 1) == 1) {          // renorm every 2 exchanges = 4 steps
          float mx = fmaxf(fmaxf(a0, a1), fmaxf(a2, a3));
          float Mx = wave_max64(mx);
          // rescale so max lands in [2^64, 2^65): exact power-of-2 scaling.
          int ee = ilogbf(fmaxf(Mx, 1.17549435e-38f)) - 64;
          float sc = ldexpf(1.0f, -ee);
          a0 *= sc; a1 *= sc; a2 *= sc; a3 *= sc;
          E += ee;
        }
      }
    }
    e += PF;
  }

  // tail: at most one leftover single step
  int t = 1 + 2 * NE;
  if (t < Tb) {
    float4 P = pb4[(size_t)t * 64 + l];
    float u3 = __shfl_up(a3, 1);
    if (l == 0) u3 = 0.f;
    float n0 = (a0 + u3) * P.x;
    float n1 = (a1 + a0 + kf5 * u3) * P.y;
    float n2 = (a2 + a1) * P.z;
    float n3 = (a3 + a2 + kf7 * a1) * P.w;
    a0 = n0; a1 = n1; a2 = n2; a3 = n3;
  }

  __shared__ float sA[260];
  sA[4 * l + 0] = a0; sA[4 * l + 1] = a1;
  sA[4 * l + 2] = a2; sA[4 * l + 3] = a3;
  __syncthreads();
  if (l == 0) {
    double ab = (double)sA[2 * Lb];       // final blank state
    double al_ = (double)sA[2 * Lb - 1];  // final label state
    costs[b] = -(log(ab + al_) + (double)E * 0.6931471805599453);
  }
}

__global__ __launch_bounds__(64) void k_final(
    const double* __restrict__ costs, const int* __restrict__ tlen,
    float* __restrict__ out, int B)
{
  int i = threadIdx.x;
  double c = (i < B) ? costs[i] : 0.0;
  double tl = (i < B) ? (double)tlen[i] : 0.0;
  #pragma unroll
  for (int o = 32; o > 0; o >>= 1) {
    c += __shfl_xor(c, o);
    tl += __shfl_xor(tl, o);
  }
  if (i == 0) out[0] = (float)(c / (double)B / tl);
}

extern "C" void kernel_launch(void* const* d_in, const int* in_sizes, int n_in,
                              void* d_out, int out_size, void* d_ws, size_t ws_size,
                              hipStream_t stream) {
  const float* act     = (const float*)d_in[0];   // [T,B,C] fp32
  const int*   targets = (const int*)d_in[1];     // [B*L]
  const int*   ilen    = (const int*)d_in[2];     // [B]
  const int*   tlen    = (const int*)d_in[3];     // [B]
  float* out = (float*)d_out;

  int B = in_sizes[2];
  int L = in_sizes[1] / B;
  const int T = 1000, C = 2000;     // fixed by the problem (in_sizes[0] = T*B*C)
  int S = 2 * L + 1;                // 201 <= 256

  float* p_ext = (float*)d_ws;                           // B*T*256 floats (~32.8 MB)
  double* costs = (double*)(p_ext + (size_t)B * T * 256); // B doubles (8B-aligned)

  k_lse_gather<<<T * B, BLK, 0, stream>>>(act, targets, p_ext, T, B, C, L, S);
  k_alpha<<<B, 64, 0, stream>>>(p_ext, targets, ilen, tlen, costs, T, B, L);
  k_final<<<1, 64, 0, stream>>>(costs, tlen, out, B);
}